// Round 6
// baseline (330.931 us; speedup 1.0000x reference)
//
#include <hip/hip_runtime.h>
#include <cstdint>
#include <cstddef>

// Instant-NGP hash-grid encode, R11 (= R10 hardened; R10 never ran —
// container-level failure, no pytest/timing output).
//
// History: R1 fused 247 us (L2 thrash). R5 split = 350.7 harness (gather
// 130.5). R6 LDS-transpose + full-line nt stores: 326.0 (gather 106).
// R7 single-phase flush: 325.1 (gather 101.4, occ 39.6%). R8 unconditional
// ws loads: REGRESSION (FETCH 2x; masked levels 8-15 must not be read).
// R9 mask-guarded batch: 326.3 (gather 106.3, VGPR 120 -> occ 21%, -5%).
// Occupancy 21..70% moves duration ~5% => pure address-path (TA/L1 line)
// throughput regime, ~2.7 cyc/CU per 64B line.
//
// R11: move dense levels 0+1 gathers onto the IDLE LDS pipe.
// Line budget/wave was: dense 20x64=1280 (88%), stores 128, x 12, ws 24.
// lv0+lv1 tables = 39.3+97.3 KB = 136.6 KB -> stage in LDS (coalesced,
// ~133 lines/wave amortized over a 1024-pt block); lv0/lv1 lookups become
// ds_read_b64 pairs. New budget ~1065 lines/wave (-26%). LDS reused for
// the output transpose after a barrier. 1024-thread blocks: 1 block/CU,
// 16 waves = 50% occ (>R9's 21%).
// Hardening vs R10: gathers consumed into o[] immediately (no ab[][]/hv[]
// arrays live across phases) -> ~70-90 VGPR, under the 128-VGPR cap that
// __launch_bounds__(1024) imposes (R10 likely spilled).

namespace {

constexpr int      kNLevels = 16;
constexpr uint32_t kT       = 1u << 19;             // 524288 entries / level
constexpr uint32_t kP1      = 2654435761u;           // tcnn hash primes (y, z)
constexpr uint32_t kP2      = 805459861u;

typedef float v2f __attribute__((ext_vector_type(2)));
typedef float v4f __attribute__((ext_vector_type(4)));

// floor(16 * scale^lv) + 1, scale = exp((ln 2048 - ln 16)/15)
__device__ constexpr int kRes[kNLevels] = {
    17, 23, 31, 43, 59, 81, 112, 154, 213, 295, 407, 562, 777, 1073, 1483, 2049
};
// dense iff res^3 <= T  <=>  res <= 80; levels 0..4 dense, 5..15 hashed.

constexpr int kN0 = 17 * 17 * 17;           // 4913 entries, lv0 (39.3 KB)
constexpr int kN1 = 23 * 23 * 23;           // 12167 entries, lv1 (97.3 KB)
constexpr int kL1Base = kN0 + 1;            // 4914: keeps lv1 base 16B-aligned
// LDS floats: table view 2*(kL1Base+kN1)=34162 -> pad 34164;
// transpose view 1024*32 = 32768. Shared region = max = 34164 floats.
constexpr int kLdsFloats = 34164;           // 136656 B <= 160 KB/CU

__device__ inline void corner_setup(float px, float py, float pz, int res,
                                    int& cx, int& cy, int& cz,
                                    float& wx, float& wy, float& wz) {
    const float s = (float)(res - 1);
    const float fx = px * s, fy = py * s, fz = pz * s;
    cx = (int)floorf(fx); cy = (int)floorf(fy); cz = (int)floorf(fz);
    cx = min(max(cx, 0), res - 2);
    cy = min(max(cy, 0), res - 2);
    cz = min(max(cz, 0), res - 2);
    wx = fx - (float)cx; wy = fy - (float)cy; wz = fz - (float)cz;
}

__device__ inline void load_xyz(const float* __restrict__ x, int p,
                                float& px, float& py, float& pz) {
    float v[3];
    __builtin_memcpy(v, x + 3 * (size_t)p, 12);   // dwordx2 + dword
    px = v[0]; py = v[1]; pz = v[2];
}

// ---------- Phase 1: hashed levels 5..15, one blockIdx.y slice per level ----
__global__ __launch_bounds__(256) void hashed_level_kernel(
    const float* __restrict__ x, const float* __restrict__ table,
    const float* __restrict__ mask, float* __restrict__ ws, int n)
{
    const int lv = 5 + blockIdx.y;
    const float m0 = mask[2 * lv], m1 = mask[2 * lv + 1];
    if (m0 == 0.0f && m1 == 0.0f) return;   // masked level: slice exits

    const int p = blockIdx.x * blockDim.x + threadIdx.x;
    if (p >= n) return;
    float px, py, pz;
    load_xyz(x, p, px, py, pz);

    const int res = kRes[lv];
    int cx, cy, cz; float wx, wy, wz;
    corner_setup(px, py, pz, res, cx, cy, cz, wx, wy, wz);
    const float ux = 1.0f - wx, uy = 1.0f - wy, uz = 1.0f - wz;
    const float* __restrict__ tbl = table + (size_t)lv * (size_t)(kT * 2);

    // hash components (CSE'd): idx = (cx+dx) ^ hy[dy] ^ hz[dz], masked
    const uint32_t hy0 = (uint32_t)cy * kP1, hy1 = (uint32_t)(cy + 1) * kP1;
    const uint32_t hz0 = (uint32_t)cz * kP2, hz1 = (uint32_t)(cz + 1) * kP2;
    const uint32_t cxu = (uint32_t)cx;

    // batch: issue all 8 gathers, then FMA
    v2f hv[8];
#pragma unroll
    for (int c = 0; c < 8; ++c) {
        const int dx = c & 1, dy = (c >> 1) & 1, dz = (c >> 2) & 1;
        const uint32_t idx =
            ((cxu + (uint32_t)dx) ^ (dy ? hy1 : hy0) ^ (dz ? hz1 : hz0))
            & (kT - 1u);
        hv[c] = *(const v2f*)(tbl + 2u * idx);
    }
    float r0 = 0.0f, r1 = 0.0f;
#pragma unroll
    for (int c = 0; c < 8; ++c) {
        const int dx = c & 1, dy = (c >> 1) & 1, dz = (c >> 2) & 1;
        const float w = (dx ? wx : ux) * (dy ? wy : uy) * (dz ? wz : uz);
        r0 = fmaf(hv[c].x, w, r0);
        r1 = fmaf(hv[c].y, w, r1);
    }
    v2f o; o.x = r0; o.y = r1;
    // full-line coalesced (64 lanes x 8 B contiguous): nt is safe here
    __builtin_nontemporal_store(
        o, (v2f*)(ws + ((size_t)(lv - 5) * n + p) * 2));
}

// ---------- Phase 2 -------------------------------------------------------
// 1024-thread blocks. Stage lv0+lv1 tables in LDS; lv0/lv1 lookups via LDS
// (off the TA pipe); lv2..4 global pair-gathers; ws readback mask-guarded.
// LDS region reused (post-barrier) for the swizzled output transpose ->
// full-line nt stores.
__global__ __launch_bounds__(1024) void gather_out_kernel(
    const float* __restrict__ x, const float* __restrict__ table,
    const float* __restrict__ ws, const float* __restrict__ mask,
    float* __restrict__ out, int n)
{
    __shared__ float lds[kLdsFloats];
    v2f* const tlds = (v2f*)lds;

    const int tid = threadIdx.x;

    // ---- stage dense tables lv0, lv1 (coalesced v2f copies) ----
    {
        const v2f* __restrict__ t0 = (const v2f*)table;
        for (int e = tid; e < kN0; e += 1024) tlds[e] = t0[e];
        const v2f* __restrict__ t1 = (const v2f*)(table + (size_t)(kT * 2));
        for (int e = tid; e < kN1; e += 1024) tlds[kL1Base + e] = t1[e];
    }

    const int p  = blockIdx.x * 1024 + tid;
    const int pc = (p < n) ? p : (n - 1);       // clamp: no early return (barriers)

    float px, py, pz;
    load_xyz(x, pc, px, py, pz);

    v4f o[8];

    // ---- dense lv2..4: global pair-gathers, consumed immediately ----
#pragma unroll
    for (int lv = 2; lv < 5; ++lv) {
        const int res = kRes[lv];
        int cx, cy, cz; float wx, wy, wz;
        corner_setup(px, py, pz, res, cx, cy, cz, wx, wy, wz);
        const float ux = 1.0f - wx, uy = 1.0f - wy, uz = 1.0f - wz;
        const float* __restrict__ tbl = table + (size_t)lv * (size_t)(kT * 2);
        const float m0 = mask[2 * lv], m1 = mask[2 * lv + 1];
        float r0 = 0.0f, r1 = 0.0f;
#pragma unroll
        for (int c = 0; c < 4; ++c) {
            const int dy = c & 1, dz = (c >> 1) & 1;
            const uint32_t idx0 =
                (uint32_t)(cx + res * ((cy + dy) + res * (cz + dz)));
            v4f ab;                              // x-corner pair: one 16 B load
            __builtin_memcpy(&ab, tbl + 2u * idx0, sizeof(v4f));
            const float wyz = (dy ? wy : uy) * (dz ? wz : uz);
            const float w0 = ux * wyz, w1 = wx * wyz;
            r0 = fmaf(ab.x, w0, fmaf(ab.z, w1, r0));
            r1 = fmaf(ab.y, w0, fmaf(ab.w, w1, r1));
        }
        r0 *= m0; r1 *= m1;
        if (lv & 1) { o[lv >> 1].z = r0; o[lv >> 1].w = r1; }
        else        { o[lv >> 1].x = r0; o[lv >> 1].y = r1; }
    }

    // ---- hashed levels 5..15: mask-guarded ws readback (R8 lesson) ----
#pragma unroll
    for (int lv = 5; lv < kNLevels; ++lv) {
        const float m0 = mask[2 * lv], m1 = mask[2 * lv + 1];
        float r0 = 0.0f, r1 = 0.0f;
        if (m0 != 0.0f || m1 != 0.0f) {
            const v2f v = __builtin_nontemporal_load(
                (const v2f*)(ws + ((size_t)(lv - 5) * n + pc) * 2));
            r0 = v.x * m0;
            r1 = v.y * m1;
        }
        if (lv & 1) { o[lv >> 1].z = r0; o[lv >> 1].w = r1; }
        else        { o[lv >> 1].x = r0; o[lv >> 1].y = r1; }
    }

    __syncthreads();                            // staged tables visible

    // ---- lv0, lv1 from LDS ----
#pragma unroll
    for (int lv = 0; lv < 2; ++lv) {
        const int res  = kRes[lv];
        const int base = lv ? kL1Base : 0;
        const float m0 = mask[2 * lv], m1 = mask[2 * lv + 1];
        int cx, cy, cz; float wx, wy, wz;
        corner_setup(px, py, pz, res, cx, cy, cz, wx, wy, wz);
        const float ux = 1.0f - wx, uy = 1.0f - wy, uz = 1.0f - wz;
        float r0 = 0.0f, r1 = 0.0f;
#pragma unroll
        for (int c = 0; c < 4; ++c) {
            const int dy = c & 1, dz = (c >> 1) & 1;
            const int idx0 = cx + res * ((cy + dy) + res * (cz + dz));
            const v2f a = tlds[base + idx0];
            const v2f b = tlds[base + idx0 + 1];
            const float wyz = (dy ? wy : uy) * (dz ? wz : uz);
            const float w0 = ux * wyz, w1 = wx * wyz;
            r0 = fmaf(a.x, w0, fmaf(b.x, w1, r0));
            r1 = fmaf(a.y, w0, fmaf(b.y, w1, r1));
        }
        r0 *= m0; r1 *= m1;
        if (lv & 1) { o[lv >> 1].z = r0; o[lv >> 1].w = r1; }
        else        { o[lv >> 1].x = r0; o[lv >> 1].y = r1; }
    }

    // ---- reuse LDS: swizzled transpose + full-line nt stores ----
    __syncthreads();                            // all table reads done
#pragma unroll
    for (int c = 0; c < 8; ++c)
        *(v4f*)&lds[tid * 32 + ((c ^ (tid & 7)) << 2)] = o[c];
    __syncthreads();

    const long long bp = (long long)blockIdx.x * 1024;
    float* const obase = out + (size_t)bp * 32;
#pragma unroll
    for (int j = 0; j < 8; ++j) {
        const int m  = tid + 1024 * j;          // 16 B chunk id, 0..8191
        const int pr = m >> 3, c = m & 7;
        if (bp + pr < n) {
            const v4f v = *(const v4f*)&lds[pr * 32 + ((c ^ (pr & 7)) << 2)];
            // 64 lanes x 16 B contiguous = full lines: nt safe
            __builtin_nontemporal_store(v, (v4f*)obase + m);
        }
    }
}

// ---------- Fallback (R1 fused kernel) if ws is too small -------------------
__global__ __launch_bounds__(256) void fused_kernel(
    const float* __restrict__ x, const float* __restrict__ table,
    const float* __restrict__ mask, float* __restrict__ out, int n)
{
    const int p = blockIdx.x * blockDim.x + threadIdx.x;
    if (p >= n) return;
    const float px = x[3 * p + 0], py = x[3 * p + 1], pz = x[3 * p + 2];
    v4f o[8];
#pragma unroll
    for (int lv = 0; lv < kNLevels; ++lv) {
        const float m0 = mask[2 * lv], m1 = mask[2 * lv + 1];
        float r0 = 0.0f, r1 = 0.0f;
        if (m0 != 0.0f || m1 != 0.0f) {
            const int res = kRes[lv];
            const bool dense = ((long long)res * res * res) <= (long long)kT;
            int cx, cy, cz; float wx, wy, wz;
            corner_setup(px, py, pz, res, cx, cy, cz, wx, wy, wz);
            const float ux = 1.0f - wx, uy = 1.0f - wy, uz = 1.0f - wz;
            const float* __restrict__ tbl = table + (size_t)lv * (size_t)(kT * 2);
#pragma unroll
            for (int c = 0; c < 8; ++c) {
                const int dx = c & 1, dy = (c >> 1) & 1, dz = (c >> 2) & 1;
                const int ix = cx + dx, iy = cy + dy, iz = cz + dz;
                uint32_t idx;
                if (dense) idx = (uint32_t)(ix + res * (iy + res * iz));
                else idx = (((uint32_t)ix) ^ ((uint32_t)iy * kP1)
                                           ^ ((uint32_t)iz * kP2)) & (kT - 1u);
                const v2f v = *(const v2f*)(tbl + 2u * idx);
                const float w = (dx ? wx : ux) * (dy ? wy : uy) * (dz ? wz : uz);
                r0 = fmaf(v.x, w, r0);
                r1 = fmaf(v.y, w, r1);
            }
            r0 *= m0; r1 *= m1;
        }
        if (lv & 1) { o[lv >> 1].z = r0; o[lv >> 1].w = r1; }
        else        { o[lv >> 1].x = r0; o[lv >> 1].y = r1; }
    }
    v4f* __restrict__ op = (v4f*)(out + (size_t)p * 32);
#pragma unroll
    for (int i = 0; i < 8; ++i) op[i] = o[i];
}

}  // namespace

extern "C" void kernel_launch(void* const* d_in, const int* in_sizes, int n_in,
                              void* d_out, int out_size, void* d_ws, size_t ws_size,
                              hipStream_t stream) {
    const float* x     = (const float*)d_in[0];
    const float* table = (const float*)d_in[1];
    const float* mask  = (const float*)d_in[2];
    float*       out   = (float*)d_out;

    const int n = in_sizes[0] / 3;  // 1048576 points
    const int block = 256;
    const int gx = (n + block - 1) / block;

    const size_t ws_needed = (size_t)(kNLevels - 5) * (size_t)n * 2 * sizeof(float);
    if (ws_size >= ws_needed) {
        float* ws = (float*)d_ws;
        dim3 grid1(gx, kNLevels - 5);   // hashed levels 5..15 as y-slices
        hashed_level_kernel<<<grid1, block, 0, stream>>>(x, table, mask, ws, n);
        const int gx2 = (n + 1023) / 1024;
        gather_out_kernel<<<gx2, 1024, 0, stream>>>(x, table, ws, mask, out, n);
    } else {
        fused_kernel<<<gx, block, 0, stream>>>(x, table, mask, out, n);
    }
}

// Round 7
// 324.789 us; speedup vs baseline: 1.0189x; 1.0189x over previous
//
#include <hip/hip_runtime.h>
#include <cstdint>
#include <cstddef>

// Instant-NGP hash-grid encode, R12 = revert to R7 (empirical best: 325.1 us
// harness, gather_out 101.4 us).
//
// History: R1 fused 247 us (L2 thrash). R5 split = 350.7 harness (gather
// 130.5). R6 LDS-transpose + full-line nt stores: 326.0 (gather 106);
// hashed even/odd-cx split (requests 512->384) = ZERO change -> hashed not
// request-count-bound. R7 single-phase flush: 325.1 (gather 101.4, occ
// 39.6%). R8 unconditional ws loads: REGRESSION (masked levels 8-15 must
// not be read). R9 mask-guarded batch: 326.3 (gather 106.3; VGPR 120 ->
// occ 21%, only -5% => throughput-, not latency-bound). R11 lv0+lv1 in
// LDS: 330.9 (gather 110.7) -- removing 512/1280 dense gather-lines bought
// NOTHING => lv0/lv1 tables (39/97 KB) were L1/L2-hot and nearly free.
//
// Conclusion: the cost lives in gathers into >L1-sized tables (lv3 0.6 MB,
// lv4 1.6 MB, hashed 4 MB) -- too big for LDS, not mergeable (R6). Store
// path at its 128-line/wave minimum. Streams minimal + mask-guarded.
// Surface is flat (101-111 us across occ 21-70%, batching, LDS offload,
// block 256-1024). R7 is the floor for this decomposition.

namespace {

constexpr int      kNLevels = 16;
constexpr uint32_t kT       = 1u << 19;             // 524288 entries / level
constexpr uint32_t kP1      = 2654435761u;           // tcnn hash primes (y, z)
constexpr uint32_t kP2      = 805459861u;

typedef float v2f __attribute__((ext_vector_type(2)));
typedef float v4f __attribute__((ext_vector_type(4)));

// floor(16 * scale^lv) + 1, scale = exp((ln 2048 - ln 16)/15)
__device__ constexpr int kRes[kNLevels] = {
    17, 23, 31, 43, 59, 81, 112, 154, 213, 295, 407, 562, 777, 1073, 1483, 2049
};
// dense iff res^3 <= T  <=>  res <= 80; levels 0..4 dense, 5..15 hashed.

__device__ inline void corner_setup(float px, float py, float pz, int res,
                                    int& cx, int& cy, int& cz,
                                    float& wx, float& wy, float& wz) {
    const float s = (float)(res - 1);
    const float fx = px * s, fy = py * s, fz = pz * s;
    cx = (int)floorf(fx); cy = (int)floorf(fy); cz = (int)floorf(fz);
    cx = min(max(cx, 0), res - 2);
    cy = min(max(cy, 0), res - 2);
    cz = min(max(cz, 0), res - 2);
    wx = fx - (float)cx; wy = fy - (float)cy; wz = fz - (float)cz;
}

__device__ inline void load_xyz(const float* __restrict__ x, int p,
                                float& px, float& py, float& pz) {
    float v[3];
    __builtin_memcpy(v, x + 3 * (size_t)p, 12);   // dwordx2 + dword
    px = v[0]; py = v[1]; pz = v[2];
}

// ---------- Phase 1: hashed levels 5..15, one blockIdx.y slice per level ----
__global__ __launch_bounds__(256) void hashed_level_kernel(
    const float* __restrict__ x, const float* __restrict__ table,
    const float* __restrict__ mask, float* __restrict__ ws, int n)
{
    const int lv = 5 + blockIdx.y;
    const float m0 = mask[2 * lv], m1 = mask[2 * lv + 1];
    if (m0 == 0.0f && m1 == 0.0f) return;   // masked level: slice exits

    const int p = blockIdx.x * blockDim.x + threadIdx.x;
    if (p >= n) return;
    float px, py, pz;
    load_xyz(x, p, px, py, pz);

    const int res = kRes[lv];
    int cx, cy, cz; float wx, wy, wz;
    corner_setup(px, py, pz, res, cx, cy, cz, wx, wy, wz);
    const float ux = 1.0f - wx, uy = 1.0f - wy, uz = 1.0f - wz;
    const float* __restrict__ tbl = table + (size_t)lv * (size_t)(kT * 2);

    // hash components (CSE'd): idx = (cx+dx) ^ hy[dy] ^ hz[dz], masked
    const uint32_t hy0 = (uint32_t)cy * kP1, hy1 = (uint32_t)(cy + 1) * kP1;
    const uint32_t hz0 = (uint32_t)cz * kP2, hz1 = (uint32_t)(cz + 1) * kP2;
    const uint32_t cxu = (uint32_t)cx;

    // batch: issue all 8 gathers, then FMA
    v2f hv[8];
#pragma unroll
    for (int c = 0; c < 8; ++c) {
        const int dx = c & 1, dy = (c >> 1) & 1, dz = (c >> 2) & 1;
        const uint32_t idx =
            ((cxu + (uint32_t)dx) ^ (dy ? hy1 : hy0) ^ (dz ? hz1 : hz0))
            & (kT - 1u);
        hv[c] = *(const v2f*)(tbl + 2u * idx);
    }
    float r0 = 0.0f, r1 = 0.0f;
#pragma unroll
    for (int c = 0; c < 8; ++c) {
        const int dx = c & 1, dy = (c >> 1) & 1, dz = (c >> 2) & 1;
        const float w = (dx ? wx : ux) * (dy ? wy : uy) * (dz ? wz : uz);
        r0 = fmaf(hv[c].x, w, r0);
        r1 = fmaf(hv[c].y, w, r1);
    }
    v2f o; o.x = r0; o.y = r1;
    // full-line coalesced (64 lanes x 8 B contiguous): nt is safe here
    __builtin_nontemporal_store(
        o, (v2f*)(ws + ((size_t)(lv - 5) * n + p) * 2));
}

// ---------- Phase 2: dense recompute + hashed readback -> out[N][32] --------
// Single-phase LDS staging (32 KB: 256 pts x 32 floats) then fully
// coalesced full-line nt stores. Swizzle: row r, 16 B chunk c lives at
// float offset r*32 + ((c ^ (r&7)) << 2) -> b128-aligned, conflict-free
// on both per-row writes and the linear copy reads (R6/R7-proven).
__global__ __launch_bounds__(256) void gather_out_kernel(
    const float* __restrict__ x, const float* __restrict__ table,
    const float* __restrict__ ws, const float* __restrict__ mask,
    float* __restrict__ out, int n)
{
    __shared__ float lds[256 * 32];             // 32 KB

    const int tid = threadIdx.x;
    const int p   = blockIdx.x * 256 + tid;
    const int pc  = (p < n) ? p : (n - 1);      // clamp: no early return (barrier)

    float px, py, pz;
    load_xyz(x, pc, px, py, pz);

    v4f o[8];

    // hashed levels 5..15 FIRST: issue ws nt-loads early so their latency
    // overlaps the dense gather work below. Mask-guarded (R8 lesson):
    // levels 8-15 are inactive -> no memory traffic.
#pragma unroll
    for (int lv = 5; lv < kNLevels; ++lv) {
        const float m0 = mask[2 * lv], m1 = mask[2 * lv + 1];
        float r0 = 0.0f, r1 = 0.0f;
        if (m0 != 0.0f || m1 != 0.0f) {
            const v2f v = __builtin_nontemporal_load(
                (const v2f*)(ws + ((size_t)(lv - 5) * n + pc) * 2));
            r0 = v.x * m0;
            r1 = v.y * m1;
        }
        if (lv & 1) { o[lv >> 1].z = r0; o[lv >> 1].w = r1; }
        else        { o[lv >> 1].x = r0; o[lv >> 1].y = r1; }
    }

    // dense levels 0..4: recompute (tables 2.65 MB, chip-wide L2-hot;
    // lv0/lv1 are L1-hot -> nearly free, R11 lesson).
#pragma unroll
    for (int lv = 0; lv < 5; ++lv) {
        const float m0 = mask[2 * lv], m1 = mask[2 * lv + 1];
        float r0 = 0.0f, r1 = 0.0f;
        if (m0 != 0.0f || m1 != 0.0f) {
            const int res = kRes[lv];
            int cx, cy, cz; float wx, wy, wz;
            corner_setup(px, py, pz, res, cx, cy, cz, wx, wy, wz);
            const float ux = 1.0f - wx, uy = 1.0f - wy, uz = 1.0f - wz;
            const float* __restrict__ tbl = table + (size_t)lv * (size_t)(kT * 2);
#pragma unroll
            for (int c = 0; c < 4; ++c) {
                const int dy = c & 1, dz = (c >> 1) & 1;
                const uint32_t idx0 =
                    (uint32_t)(cx + res * ((cy + dy) + res * (cz + dz)));
                // entries idx0 and idx0+1 are the two x-corners: one 16 B load
                v4f ab;
                __builtin_memcpy(&ab, tbl + 2u * idx0, sizeof(v4f));
                const float wyz = (dy ? wy : uy) * (dz ? wz : uz);
                const float w0 = ux * wyz, w1 = wx * wyz;
                r0 = fmaf(ab.x, w0, fmaf(ab.z, w1, r0));
                r1 = fmaf(ab.y, w0, fmaf(ab.w, w1, r1));
            }
            r0 *= m0; r1 *= m1;
        }
        if (lv & 1) { o[lv >> 1].z = r0; o[lv >> 1].w = r1; }
        else        { o[lv >> 1].x = r0; o[lv >> 1].y = r1; }
    }

    // ---- single-phase LDS transpose + coalesced full-line nt stores ----
#pragma unroll
    for (int c = 0; c < 8; ++c)
        *(v4f*)&lds[tid * 32 + ((c ^ (tid & 7)) << 2)] = o[c];
    __syncthreads();

    const long long bp = (long long)blockIdx.x * 256;
    float* const obase = out + (size_t)bp * 32;
#pragma unroll
    for (int j = 0; j < 8; ++j) {
        const int m  = tid + 256 * j;           // 16 B chunk id, 0..2047
        const int pr = m >> 3, c = m & 7;
        if (bp + pr < n) {
            const v4f v = *(const v4f*)&lds[pr * 32 + ((c ^ (pr & 7)) << 2)];
            // 64 lanes x 16 B contiguous = full lines: nt safe
            __builtin_nontemporal_store(v, (v4f*)obase + m);
        }
    }
}

// ---------- Fallback (R1 fused kernel) if ws is too small -------------------
__global__ __launch_bounds__(256) void fused_kernel(
    const float* __restrict__ x, const float* __restrict__ table,
    const float* __restrict__ mask, float* __restrict__ out, int n)
{
    const int p = blockIdx.x * blockDim.x + threadIdx.x;
    if (p >= n) return;
    const float px = x[3 * p + 0], py = x[3 * p + 1], pz = x[3 * p + 2];
    v4f o[8];
#pragma unroll
    for (int lv = 0; lv < kNLevels; ++lv) {
        const float m0 = mask[2 * lv], m1 = mask[2 * lv + 1];
        float r0 = 0.0f, r1 = 0.0f;
        if (m0 != 0.0f || m1 != 0.0f) {
            const int res = kRes[lv];
            const bool dense = ((long long)res * res * res) <= (long long)kT;
            int cx, cy, cz; float wx, wy, wz;
            corner_setup(px, py, pz, res, cx, cy, cz, wx, wy, wz);
            const float ux = 1.0f - wx, uy = 1.0f - wy, uz = 1.0f - wz;
            const float* __restrict__ tbl = table + (size_t)lv * (size_t)(kT * 2);
#pragma unroll
            for (int c = 0; c < 8; ++c) {
                const int dx = c & 1, dy = (c >> 1) & 1, dz = (c >> 2) & 1;
                const int ix = cx + dx, iy = cy + dy, iz = cz + dz;
                uint32_t idx;
                if (dense) idx = (uint32_t)(ix + res * (iy + res * iz));
                else idx = (((uint32_t)ix) ^ ((uint32_t)iy * kP1)
                                           ^ ((uint32_t)iz * kP2)) & (kT - 1u);
                const v2f v = *(const v2f*)(tbl + 2u * idx);
                const float w = (dx ? wx : ux) * (dy ? wy : uy) * (dz ? wz : uz);
                r0 = fmaf(v.x, w, r0);
                r1 = fmaf(v.y, w, r1);
            }
            r0 *= m0; r1 *= m1;
        }
        if (lv & 1) { o[lv >> 1].z = r0; o[lv >> 1].w = r1; }
        else        { o[lv >> 1].x = r0; o[lv >> 1].y = r1; }
    }
    v4f* __restrict__ op = (v4f*)(out + (size_t)p * 32);
#pragma unroll
    for (int i = 0; i < 8; ++i) op[i] = o[i];
}

}  // namespace

extern "C" void kernel_launch(void* const* d_in, const int* in_sizes, int n_in,
                              void* d_out, int out_size, void* d_ws, size_t ws_size,
                              hipStream_t stream) {
    const float* x     = (const float*)d_in[0];
    const float* table = (const float*)d_in[1];
    const float* mask  = (const float*)d_in[2];
    float*       out   = (float*)d_out;

    const int n = in_sizes[0] / 3;  // 1048576 points
    const int block = 256;
    const int gx = (n + block - 1) / block;

    const size_t ws_needed = (size_t)(kNLevels - 5) * (size_t)n * 2 * sizeof(float);
    if (ws_size >= ws_needed) {
        float* ws = (float*)d_ws;
        dim3 grid1(gx, kNLevels - 5);   // hashed levels 5..15 as y-slices
        hashed_level_kernel<<<grid1, block, 0, stream>>>(x, table, mask, ws, n);
        gather_out_kernel<<<gx, block, 0, stream>>>(x, table, ws, mask, out, n);
    } else {
        fused_kernel<<<gx, block, 0, stream>>>(x, table, mask, out, n);
    }
}